// Round 8
// baseline (141.114 us; speedup 1.0000x reference)
//
#include <hip/hip_runtime.h>
#include <stdint.h>
#include <math.h>

// ---------------------------------------------------------------------------
// SelfAttention: X[4,2048,1024] f32; Wq/Wk/Wv [1024,128] f32
// O = softmax(XWq (XWk)^T / sqrt(128)) XWv      (no mask)
// x32 MFMA proj (64x128 block, 32x64 wave) ; flash with 32 q-rows/wave,
// NSPLIT=8, exp2-domain softmax (scale*log2e folded into Wq), defer-max,
// setprio around MFMA clusters.  exp2f() == native v_exp_f32 on gfx950.
// ---------------------------------------------------------------------------

typedef __attribute__((ext_vector_type(4))) float  f32x4;
typedef __attribute__((ext_vector_type(4))) short  s16x4;
typedef __attribute__((ext_vector_type(8))) short  s16x8;
typedef __attribute__((ext_vector_type(4))) float  fl4;

#define MFMA16(a,b,c) __builtin_amdgcn_mfma_f32_16x16x16bf16_1k(a,b,c,0,0,0)
#define MFMA32(a,b,c) __builtin_amdgcn_mfma_f32_16x16x32_bf16(a,b,c,0,0,0)

__device__ __forceinline__ short f2bf(float f){
  uint32_t u = __builtin_bit_cast(uint32_t, f);
  u = (u + 0x7FFFu + ((u >> 16) & 1u)) >> 16;   // RNE
  return (short)u;
}

#define S_LEN   2048
#define D_IN    1024
#define D_HEAD  128
#define NROWS   8192      // B*S
#define NSPLIT  8
#define KVB     64
#define KVPER   (S_LEN / NSPLIT)   // 256
#define NT      (KVPER / KVB)      // 4
#define QBLK    128                // 4 waves * 32 q rows

// ws layout (bytes)
#define WT_OFF  0u                        // 3*128*1024*2      = 786432
#define Q_OFF   786432u                   // 8192*128*2        = 2097152
#define K_OFF   (786432u + 2097152u)
#define V_OFF   (786432u + 2u*2097152u)
#define OP_OFF  (786432u + 3u*2097152u)   // 8*8192*128*4      = 33554432
#define ML_OFF  (OP_OFF + 33554432u)      // 8*8192*2*4        = 524288
// total ~41.2 MB

// log2(e), defer-max threshold (= 8 nats) in log2 domain
#define LOG2E   1.4426950408889634f
#define DEFER_TH 11.541560327111708f

// ---------------------------------------------------------------------------
// Kernel 1: W [1024][128] f32 -> Wt [3][128][1024] bf16 (transpose+convert).
// scale * log2(e) folded into Wq (softmax runs in exp2 domain).
// ---------------------------------------------------------------------------
__global__ __launch_bounds__(256) void wt3_kernel(
    const float* __restrict__ Wq, const float* __restrict__ Wk,
    const float* __restrict__ Wv, short* __restrict__ Wt){
  int i = blockIdx.x * 256 + threadIdx.x;    // < 3*131072
  int m = i >> 17;
  int r = i & 131071;
  int n = r >> 10;          // 0..127
  int k = r & 1023;         // 0..1023
  const float* W = (m == 0) ? Wq : (m == 1 ? Wk : Wv);
  float v = W[k * D_HEAD + n];
  if (m == 0) v *= 0.08838834764831845f * LOG2E;
  Wt[i] = f2bf(v);
}

// ---------------------------------------------------------------------------
// Kernel 2: projection GEMM. grid (128 m-tiles of 64 rows, 3 mats), 4 waves.
// Block tile 64x128, wave tile 32x64 (2x4 frags), BK=64, x32 MFMA, prefetch.
// mat 0 -> Q bf16 [8192][128]; 1 -> K; 2 -> V^T bf16 [4][128][2048]
// ---------------------------------------------------------------------------
__global__ __launch_bounds__(256) void proj_kernel(
    const float* __restrict__ X, const short* __restrict__ Wt,
    short* __restrict__ Qo, short* __restrict__ Ko, short* __restrict__ Vt){
  const int mt  = blockIdx.x;     // 0..127 (64-row tiles)
  const int mat = blockIdx.y;
  const short* Wm = Wt + mat * 131072;

  __shared__ short Xs[64][72];    // 64x64 bf16 tile (144B stride)
  __shared__ short Ws[128][72];   // 128x64 bf16 tile of W^T

  const int tid  = threadIdx.x;
  const int lane = tid & 63;
  const int wid  = tid >> 6;
  const int wm   = (wid >> 1) * 32;   // 0/32
  const int wn   = (wid & 1) * 64;    // 0/64
  const int lr   = lane & 15;
  const int lg8  = (lane >> 4) * 8;

  const f32x4 zero4 = {0.f, 0.f, 0.f, 0.f};
  f32x4 acc[2][4];
  #pragma unroll
  for (int mf = 0; mf < 2; mf++)
    #pragma unroll
    for (int n = 0; n < 4; n++) acc[mf][n] = zero4;

  // staging coords
  const int xr = tid >> 2, xc = (tid & 3) * 16;    // X: 64x64, 16 f32/thread
  const int wr = tid >> 1, wc = (tid & 1) * 32;    // W: 128x64, 32 bf16/thread

  const float* xsrc0 = X + (size_t)(mt * 64 + xr) * D_IN + xc;
  const short* wsrc0 = Wm + (size_t)wr * D_IN + wc;

  fl4   xA[4];
  s16x8 wR[4];

  // preload k-step 0
  #pragma unroll
  for (int j = 0; j < 4; j++){
    xA[j] = *(const fl4*)(xsrc0 + 4 * j);
    wR[j] = *(const s16x8*)(wsrc0 + 8 * j);
  }

  #pragma unroll 1
  for (int kt = 0; kt < D_IN; kt += 64){
    { // write staged tile
      s16x8 v0, v1;
      #pragma unroll
      for (int j = 0; j < 4; j++){
        v0[j] = f2bf(xA[0][j]); v0[j+4] = f2bf(xA[1][j]);
        v1[j] = f2bf(xA[2][j]); v1[j+4] = f2bf(xA[3][j]);
      }
      *(s16x8*)&Xs[xr][xc]     = v0;
      *(s16x8*)&Xs[xr][xc + 8] = v1;
      #pragma unroll
      for (int j = 0; j < 4; j++) *(s16x8*)&Ws[wr][wc + 8*j] = wR[j];
    }
    __syncthreads();

    // prefetch next k-step
    if (kt + 64 < D_IN){
      #pragma unroll
      for (int j = 0; j < 4; j++){
        xA[j] = *(const fl4*)(xsrc0 + kt + 64 + 4*j);
        wR[j] = *(const s16x8*)(wsrc0 + kt + 64 + 8*j);
      }
    }

    #pragma unroll
    for (int kc = 0; kc < 64; kc += 32){
      s16x8 af[2];
      #pragma unroll
      for (int mf = 0; mf < 2; mf++)
        af[mf] = *(const s16x8*)&Xs[wm + mf*16 + lr][kc + lg8];
      #pragma unroll
      for (int n = 0; n < 4; n++){
        s16x8 bf = *(const s16x8*)&Ws[wn + n*16 + lr][kc + lg8];
        #pragma unroll
        for (int mf = 0; mf < 2; mf++)
          acc[mf][n] = MFMA32(af[mf], bf, acc[mf][n]);
      }
    }
    __syncthreads();
  }

  const int lg4 = (lane >> 4) * 4;
  if (mat < 2){
    short* dst = (mat == 0) ? Qo : Ko;
    #pragma unroll
    for (int mf = 0; mf < 2; mf++)
      #pragma unroll
      for (int n = 0; n < 4; n++){
        int col = wn + n*16 + lr;
        #pragma unroll
        for (int r = 0; r < 4; r++){
          int row = mt*64 + wm + mf*16 + lg4 + r;
          dst[(size_t)row * D_HEAD + col] = f2bf(acc[mf][n][r]);
        }
      }
  } else {
    const int b  = (mt * 64) >> 11;
    const int s0 = (mt * 64) & 2047;
    #pragma unroll
    for (int mf = 0; mf < 2; mf++)
      #pragma unroll
      for (int n = 0; n < 4; n++){
        int dv = wn + n*16 + lr;
        int s  = s0 + wm + mf*16 + lg4;
        s16x4 v;
        #pragma unroll
        for (int r = 0; r < 4; r++) v[r] = f2bf(acc[mf][n][r]);
        *(s16x4*)&Vt[((size_t)b * D_HEAD + dv) * S_LEN + s] = v;
      }
  }
}

// ---------------------------------------------------------------------------
// Kernel 3: flash attention, KV split. grid (NSPLIT=8, 16, 4), 4 waves.
// Wave = 32 q rows (2 q-frag columns share every K/V LDS read).
// KVB=64, x32 QK^T, x16 PV, reg prefetch, defer-max, exp2-domain softmax.
// ---------------------------------------------------------------------------
__global__ __launch_bounds__(256) void flash_kernel(
    const short* __restrict__ Q, const short* __restrict__ K,
    const short* __restrict__ Vt, float* __restrict__ Opart,
    float* __restrict__ MLpart){
  const int sp = blockIdx.x;
  const int qt = blockIdx.y;
  const int b  = blockIdx.z;

  __shared__ short Ks[KVB][136];   // 64 x 128 bf16 (272B stride)
  __shared__ short Vs[128][72];    // V^T tile: 128 dv x 64 kv (144B stride)

  const int tid  = threadIdx.x;
  const int lane = tid & 63;
  const int w    = tid >> 6;
  const int lr   = lane & 15;
  const int lg   = lane >> 4;

  // Q fragments: 2 q-frag columns per wave (rows qrow0 and qrow0+16)
  const int qrow0 = qt * QBLK + w * 32 + lr;
  const short* Qr = Q + (size_t)(b * S_LEN + qrow0) * D_HEAD + 8 * lg;
  s16x8 qf[2][4];
  #pragma unroll
  for (int qi = 0; qi < 2; qi++)
    #pragma unroll
    for (int c = 0; c < 4; c++)
      qf[qi][c] = *(const s16x8*)(Qr + qi * 16 * D_HEAD + c * 32);

  const f32x4 zero4 = {0.f, 0.f, 0.f, 0.f};
  f32x4 o[2][8];
  #pragma unroll
  for (int qi = 0; qi < 2; qi++)
    #pragma unroll
    for (int t = 0; t < 8; t++) o[qi][t] = zero4;
  float m_run[2] = {-INFINITY, -INFINITY};
  float l_run[2] = {0.0f, 0.0f};

  const short* Kb = K  + (size_t)b * S_LEN * D_HEAD;
  const short* Vb = Vt + (size_t)b * D_HEAD * S_LEN;
  const int kr = tid >> 2, kc = (tid & 3) * 32;   // K tile 64x128
  const int vr = tid >> 1, vc = (tid & 1) * 32;   // V^T tile 128x64

  s16x8 kR[4], vR[4];
  const int kv_beg = sp * KVPER;

  { // preload tile 0
    const short* ks = Kb + (size_t)(kv_beg + kr) * D_HEAD + kc;
    const short* vs = Vb + (size_t)vr * S_LEN + kv_beg + vc;
    #pragma unroll
    for (int j = 0; j < 4; j++){
      kR[j] = *(const s16x8*)(ks + 8*j);
      vR[j] = *(const s16x8*)(vs + 8*j);
    }
  }
  #pragma unroll
  for (int j = 0; j < 4; j++){
    *(s16x8*)&Ks[kr][kc + 8*j] = kR[j];
    *(s16x8*)&Vs[vr][vc + 8*j] = vR[j];
  }
  __syncthreads();

  #pragma unroll 1
  for (int it = 0; it < NT; ++it){
    // prefetch next tile into regs
    if (it + 1 < NT){
      int kv0 = kv_beg + (it + 1) * KVB;
      const short* ks = Kb + (size_t)(kv0 + kr) * D_HEAD + kc;
      const short* vs = Vb + (size_t)vr * S_LEN + kv0 + vc;
      #pragma unroll
      for (int j = 0; j < 4; j++){
        kR[j] = *(const s16x8*)(ks + 8*j);
        vR[j] = *(const s16x8*)(vs + 8*j);
      }
    }

    // S^T = K * Q^T (x32): lane holds S[kv = 4*lg+r + 16*t][q = lr + 16*qi]
    f32x4 sa[2][4];
    #pragma unroll
    for (int qi = 0; qi < 2; qi++)
      #pragma unroll
      for (int t = 0; t < 4; t++) sa[qi][t] = zero4;
    __builtin_amdgcn_s_setprio(1);
    #pragma unroll
    for (int c = 0; c < 4; c++){
      #pragma unroll
      for (int t = 0; t < 4; t++){
        s16x8 ka = *(const s16x8*)&Ks[t*16 + lr][c*32 + 8*lg];
        sa[0][t] = MFMA32(ka, qf[0][c], sa[0][t]);
        sa[1][t] = MFMA32(ka, qf[1][c], sa[1][t]);
      }
    }
    __builtin_amdgcn_s_setprio(0);

    // online softmax in exp2 domain (scale*log2e folded into Wq)
    s16x4 pb[2][4];
    #pragma unroll
    for (int qi = 0; qi < 2; qi++){
      float mx = -INFINITY;
      #pragma unroll
      for (int t = 0; t < 4; t++)
        #pragma unroll
        for (int r = 0; r < 4; r++) mx = fmaxf(mx, sa[qi][t][r]);
      mx = fmaxf(mx, __shfl_xor(mx, 16));
      mx = fmaxf(mx, __shfl_xor(mx, 32));
      if (!__all(mx <= m_run[qi] + DEFER_TH)){   // defer-max: rescale rarely
        float m_new = fmaxf(m_run[qi], mx);
        float alpha = exp2f(m_run[qi] - m_new);  // first tile: exp2(-inf)=0
        l_run[qi] *= alpha;
        #pragma unroll
        for (int t = 0; t < 8; t++) o[qi][t] *= alpha;
        m_run[qi] = m_new;
      }
      float lsum = 0.0f;
      #pragma unroll
      for (int t = 0; t < 4; t++)
        #pragma unroll
        for (int r = 0; r < 4; r++){
          float e = exp2f(sa[qi][t][r] - m_run[qi]);
          pb[qi][t][r] = f2bf(e);
          lsum += e;
        }
      lsum += __shfl_xor(lsum, 16);
      lsum += __shfl_xor(lsum, 32);
      l_run[qi] += lsum;
    }

    // O^T += V^T * P^T (x16): va reused by both q-frag columns
    __builtin_amdgcn_s_setprio(1);
    #pragma unroll
    for (int dt = 0; dt < 8; dt++){
      #pragma unroll
      for (int t = 0; t < 4; t++){
        s16x4 va = *(const s16x4*)&Vs[dt*16 + lr][t*16 + 4*lg];
        o[0][dt] = MFMA16(va, pb[0][t], o[0][dt]);
        o[1][dt] = MFMA16(va, pb[1][t], o[1][dt]);
      }
    }
    __builtin_amdgcn_s_setprio(0);

    if (it + 1 < NT){
      __syncthreads();                 // all waves done reading LDS
      #pragma unroll
      for (int j = 0; j < 4; j++){
        *(s16x8*)&Ks[kr][kc + 8*j] = kR[j];
        *(s16x8*)&Vs[vr][vc + 8*j] = vR[j];
      }
      __syncthreads();                 // LDS ready
    }
  }

  const int lg4 = lg * 4;
  #pragma unroll
  for (int qi = 0; qi < 2; qi++){
    const size_t grow = (size_t)b * S_LEN + qrow0 + qi * 16;
    float* Op = Opart + ((size_t)sp * NROWS + grow) * D_HEAD + lg4;
    #pragma unroll
    for (int dt = 0; dt < 8; dt++)
      *(f32x4*)(Op + dt * 16) = o[qi][dt];
    if (lg == 0){
      float* ml = MLpart + ((size_t)sp * NROWS + grow) * 2;
      ml[0] = m_run[qi]; ml[1] = l_run[qi];
    }
  }
}

// ---------------------------------------------------------------------------
// Kernel 4: merge the NSPLIT partials (exp2 domain).
// ---------------------------------------------------------------------------
__global__ __launch_bounds__(256) void merge_kernel(
    const float* __restrict__ Opart, const float* __restrict__ MLpart,
    float* __restrict__ out){
  int idx = blockIdx.x * 256 + threadIdx.x;    // < 8192*128
  int row = idx >> 7;
  float m[NSPLIT], l[NSPLIT];
  float M = -INFINITY;
  #pragma unroll
  for (int s = 0; s < NSPLIT; s++){
    m[s] = MLpart[((size_t)s * NROWS + row) * 2 + 0];
    l[s] = MLpart[((size_t)s * NROWS + row) * 2 + 1];
    M = fmaxf(M, m[s]);
  }
  float L = 0.f, val = 0.f;
  #pragma unroll
  for (int s = 0; s < NSPLIT; s++){
    float e = exp2f(m[s] - M);
    L   += l[s] * e;
    val += Opart[(size_t)s * NROWS * D_HEAD + idx] * e;
  }
  out[idx] = val / L;
}

// ---------------------------------------------------------------------------
extern "C" void kernel_launch(void* const* d_in, const int* in_sizes, int n_in,
                              void* d_out, int out_size, void* d_ws, size_t ws_size,
                              hipStream_t stream){
  const float* X  = (const float*)d_in[0];
  const float* Wq = (const float*)d_in[1];
  const float* Wk = (const float*)d_in[2];
  const float* Wv = (const float*)d_in[3];
  char* ws = (char*)d_ws;
  short* Wt = (short*)(ws + WT_OFF);
  short* Qp = (short*)(ws + Q_OFF);
  short* Kp = (short*)(ws + K_OFF);
  short* Vt = (short*)(ws + V_OFF);
  float* Op = (float*)(ws + OP_OFF);
  float* Ml = (float*)(ws + ML_OFF);
  float* out = (float*)d_out;

  wt3_kernel  <<<dim3(1536),           dim3(256), 0, stream>>>(Wq, Wk, Wv, Wt);
  proj_kernel <<<dim3(128, 3),         dim3(256), 0, stream>>>(X, Wt, Qp, Kp, Vt);
  flash_kernel<<<dim3(NSPLIT, 16, 4),  dim3(256), 0, stream>>>(Qp, Kp, Vt, Op, Ml);
  merge_kernel<<<dim3(4096),           dim3(256), 0, stream>>>(Op, Ml, out);
}

// Round 9
// 129.047 us; speedup vs baseline: 1.0935x; 1.0935x over previous
//
#include <hip/hip_runtime.h>
#include <stdint.h>
#include <math.h>

// ---------------------------------------------------------------------------
// SelfAttention: X[4,2048,1024] f32; Wq/Wk/Wv [1024,128] f32
// O = softmax(XWq (XWk)^T / sqrt(128)) XWv      (no mask)
// proj: x32 MFMA, 64x128 block, 32x64 wave tile.
// flash: 16 q-rows/wave, QBLK=64, NSPLIT=8 -> grid 1024 (4 blocks/CU, LDS-max
// residency), exp2-domain softmax, defer-max, setprio, reg prefetch.
// ---------------------------------------------------------------------------

typedef __attribute__((ext_vector_type(4))) float  f32x4;
typedef __attribute__((ext_vector_type(4))) short  s16x4;
typedef __attribute__((ext_vector_type(8))) short  s16x8;
typedef __attribute__((ext_vector_type(4))) float  fl4;

#define MFMA16(a,b,c) __builtin_amdgcn_mfma_f32_16x16x16bf16_1k(a,b,c,0,0,0)
#define MFMA32(a,b,c) __builtin_amdgcn_mfma_f32_16x16x32_bf16(a,b,c,0,0,0)

__device__ __forceinline__ short f2bf(float f){
  uint32_t u = __builtin_bit_cast(uint32_t, f);
  u = (u + 0x7FFFu + ((u >> 16) & 1u)) >> 16;   // RNE
  return (short)u;
}

#define S_LEN   2048
#define D_IN    1024
#define D_HEAD  128
#define NROWS   8192      // B*S
#define NSPLIT  8
#define KVB     64
#define KVPER   (S_LEN / NSPLIT)   // 256
#define NT      (KVPER / KVB)      // 4
#define QBLK    64                 // 4 waves * 16 q rows

// ws layout (bytes)
#define WT_OFF  0u                        // 3*128*1024*2      = 786432
#define Q_OFF   786432u                   // 8192*128*2        = 2097152
#define K_OFF   (786432u + 2097152u)
#define V_OFF   (786432u + 2u*2097152u)
#define OP_OFF  (786432u + 3u*2097152u)   // 8*8192*128*4      = 33554432
#define ML_OFF  (OP_OFF + 33554432u)      // 8*8192*2*4        = 524288
// total ~41.2 MB

// log2(e), defer-max threshold (= 8 nats) in log2 domain
#define LOG2E   1.4426950408889634f
#define DEFER_TH 11.541560327111708f

// ---------------------------------------------------------------------------
// Kernel 1: W [1024][128] f32 -> Wt [3][128][1024] bf16 (transpose+convert).
// scale * log2(e) folded into Wq (softmax runs in exp2 domain).
// ---------------------------------------------------------------------------
__global__ __launch_bounds__(256) void wt3_kernel(
    const float* __restrict__ Wq, const float* __restrict__ Wk,
    const float* __restrict__ Wv, short* __restrict__ Wt){
  int i = blockIdx.x * 256 + threadIdx.x;    // < 3*131072
  int m = i >> 17;
  int r = i & 131071;
  int n = r >> 10;          // 0..127
  int k = r & 1023;         // 0..1023
  const float* W = (m == 0) ? Wq : (m == 1 ? Wk : Wv);
  float v = W[k * D_HEAD + n];
  if (m == 0) v *= 0.08838834764831845f * LOG2E;
  Wt[i] = f2bf(v);
}

// ---------------------------------------------------------------------------
// Kernel 2: projection GEMM. grid (128 m-tiles of 64 rows, 3 mats), 4 waves.
// Block tile 64x128, wave tile 32x64 (2x4 frags), BK=64, x32 MFMA, prefetch.
// mat 0 -> Q bf16 [8192][128]; 1 -> K; 2 -> V^T bf16 [4][128][2048]
// ---------------------------------------------------------------------------
__global__ __launch_bounds__(256) void proj_kernel(
    const float* __restrict__ X, const short* __restrict__ Wt,
    short* __restrict__ Qo, short* __restrict__ Ko, short* __restrict__ Vt){
  const int mt  = blockIdx.x;     // 0..127 (64-row tiles)
  const int mat = blockIdx.y;
  const short* Wm = Wt + mat * 131072;

  __shared__ short Xs[64][72];    // 64x64 bf16 tile (144B stride)
  __shared__ short Ws[128][72];   // 128x64 bf16 tile of W^T

  const int tid  = threadIdx.x;
  const int lane = tid & 63;
  const int wid  = tid >> 6;
  const int wm   = (wid >> 1) * 32;   // 0/32
  const int wn   = (wid & 1) * 64;    // 0/64
  const int lr   = lane & 15;
  const int lg8  = (lane >> 4) * 8;

  const f32x4 zero4 = {0.f, 0.f, 0.f, 0.f};
  f32x4 acc[2][4];
  #pragma unroll
  for (int mf = 0; mf < 2; mf++)
    #pragma unroll
    for (int n = 0; n < 4; n++) acc[mf][n] = zero4;

  // staging coords
  const int xr = tid >> 2, xc = (tid & 3) * 16;    // X: 64x64, 16 f32/thread
  const int wr = tid >> 1, wc = (tid & 1) * 32;    // W: 128x64, 32 bf16/thread

  const float* xsrc0 = X + (size_t)(mt * 64 + xr) * D_IN + xc;
  const short* wsrc0 = Wm + (size_t)wr * D_IN + wc;

  fl4   xA[4];
  s16x8 wR[4];

  // preload k-step 0
  #pragma unroll
  for (int j = 0; j < 4; j++){
    xA[j] = *(const fl4*)(xsrc0 + 4 * j);
    wR[j] = *(const s16x8*)(wsrc0 + 8 * j);
  }

  #pragma unroll 1
  for (int kt = 0; kt < D_IN; kt += 64){
    { // write staged tile
      s16x8 v0, v1;
      #pragma unroll
      for (int j = 0; j < 4; j++){
        v0[j] = f2bf(xA[0][j]); v0[j+4] = f2bf(xA[1][j]);
        v1[j] = f2bf(xA[2][j]); v1[j+4] = f2bf(xA[3][j]);
      }
      *(s16x8*)&Xs[xr][xc]     = v0;
      *(s16x8*)&Xs[xr][xc + 8] = v1;
      #pragma unroll
      for (int j = 0; j < 4; j++) *(s16x8*)&Ws[wr][wc + 8*j] = wR[j];
    }
    __syncthreads();

    // prefetch next k-step
    if (kt + 64 < D_IN){
      #pragma unroll
      for (int j = 0; j < 4; j++){
        xA[j] = *(const fl4*)(xsrc0 + kt + 64 + 4*j);
        wR[j] = *(const s16x8*)(wsrc0 + kt + 64 + 8*j);
      }
    }

    #pragma unroll
    for (int kc = 0; kc < 64; kc += 32){
      s16x8 af[2];
      #pragma unroll
      for (int mf = 0; mf < 2; mf++)
        af[mf] = *(const s16x8*)&Xs[wm + mf*16 + lr][kc + lg8];
      #pragma unroll
      for (int n = 0; n < 4; n++){
        s16x8 bf = *(const s16x8*)&Ws[wn + n*16 + lr][kc + lg8];
        #pragma unroll
        for (int mf = 0; mf < 2; mf++)
          acc[mf][n] = MFMA32(af[mf], bf, acc[mf][n]);
      }
    }
    __syncthreads();
  }

  const int lg4 = (lane >> 4) * 4;
  if (mat < 2){
    short* dst = (mat == 0) ? Qo : Ko;
    #pragma unroll
    for (int mf = 0; mf < 2; mf++)
      #pragma unroll
      for (int n = 0; n < 4; n++){
        int col = wn + n*16 + lr;
        #pragma unroll
        for (int r = 0; r < 4; r++){
          int row = mt*64 + wm + mf*16 + lg4 + r;
          dst[(size_t)row * D_HEAD + col] = f2bf(acc[mf][n][r]);
        }
      }
  } else {
    const int b  = (mt * 64) >> 11;
    const int s0 = (mt * 64) & 2047;
    #pragma unroll
    for (int mf = 0; mf < 2; mf++)
      #pragma unroll
      for (int n = 0; n < 4; n++){
        int dv = wn + n*16 + lr;
        int s  = s0 + wm + mf*16 + lg4;
        s16x4 v;
        #pragma unroll
        for (int r = 0; r < 4; r++) v[r] = f2bf(acc[mf][n][r]);
        *(s16x4*)&Vt[((size_t)b * D_HEAD + dv) * S_LEN + s] = v;
      }
  }
}

// ---------------------------------------------------------------------------
// Kernel 3: flash attention, KV split. grid (NSPLIT=8, 32, 4) = 1024 blocks
// (4 blocks/CU = LDS-max residency). 4 waves, 16 q rows each.
// KVB=64, x32 QK^T, x16 PV (P direct from regs), reg prefetch, defer-max.
// ---------------------------------------------------------------------------
__global__ __launch_bounds__(256, 4) void flash_kernel(
    const short* __restrict__ Q, const short* __restrict__ K,
    const short* __restrict__ Vt, float* __restrict__ Opart,
    float* __restrict__ MLpart){
  const int sp = blockIdx.x;
  const int qt = blockIdx.y;
  const int b  = blockIdx.z;

  __shared__ short Ks[KVB][136];   // 64 x 128 bf16 (272B stride)
  __shared__ short Vs[128][72];    // V^T tile: 128 dv x 64 kv (144B stride)

  const int tid  = threadIdx.x;
  const int lane = tid & 63;
  const int w    = tid >> 6;
  const int lr   = lane & 15;
  const int lg   = lane >> 4;

  // Q fragments (B operand of QK^T): row q=lr, 8 contiguous d at c*32+8*lg
  const int qrow = qt * QBLK + w * 16 + lr;
  const short* Qr = Q + (size_t)(b * S_LEN + qrow) * D_HEAD + 8 * lg;
  s16x8 qf[4];
  #pragma unroll
  for (int c = 0; c < 4; c++) qf[c] = *(const s16x8*)(Qr + c * 32);

  const f32x4 zero4 = {0.f, 0.f, 0.f, 0.f};
  f32x4 o[8];
  #pragma unroll
  for (int t = 0; t < 8; t++) o[t] = zero4;
  float m_run = -INFINITY, l_run = 0.0f;

  const short* Kb = K  + (size_t)b * S_LEN * D_HEAD;
  const short* Vb = Vt + (size_t)b * D_HEAD * S_LEN;
  const int kr = tid >> 2, kc = (tid & 3) * 32;   // K tile 64x128
  const int vr = tid >> 1, vc = (tid & 1) * 32;   // V^T tile 128x64

  s16x8 kR[4], vR[4];
  const int kv_beg = sp * KVPER;

  { // preload tile 0
    const short* ks = Kb + (size_t)(kv_beg + kr) * D_HEAD + kc;
    const short* vs = Vb + (size_t)vr * S_LEN + kv_beg + vc;
    #pragma unroll
    for (int j = 0; j < 4; j++){
      kR[j] = *(const s16x8*)(ks + 8*j);
      vR[j] = *(const s16x8*)(vs + 8*j);
    }
  }
  #pragma unroll
  for (int j = 0; j < 4; j++){
    *(s16x8*)&Ks[kr][kc + 8*j] = kR[j];
    *(s16x8*)&Vs[vr][vc + 8*j] = vR[j];
  }
  __syncthreads();

  #pragma unroll 1
  for (int it = 0; it < NT; ++it){
    // prefetch next tile into regs (global latency hides under compute)
    if (it + 1 < NT){
      int kv0 = kv_beg + (it + 1) * KVB;
      const short* ks = Kb + (size_t)(kv0 + kr) * D_HEAD + kc;
      const short* vs = Vb + (size_t)vr * S_LEN + kv0 + vc;
      #pragma unroll
      for (int j = 0; j < 4; j++){
        kR[j] = *(const s16x8*)(ks + 8*j);
        vR[j] = *(const s16x8*)(vs + 8*j);
      }
    }

    // S^T = K * Q^T (x32): lane holds S[kv = 4*lg+r + 16*t][q = lr]
    f32x4 sa[4];
    #pragma unroll
    for (int t = 0; t < 4; t++) sa[t] = zero4;
    __builtin_amdgcn_s_setprio(1);
    #pragma unroll
    for (int c = 0; c < 4; c++){
      #pragma unroll
      for (int t = 0; t < 4; t++){
        s16x8 ka = *(const s16x8*)&Ks[t*16 + lr][c*32 + 8*lg];
        sa[t] = MFMA32(ka, qf[c], sa[t]);
      }
    }
    __builtin_amdgcn_s_setprio(0);

    // online softmax in exp2 domain (scale*log2e folded into Wq)
    float mx = -INFINITY;
    #pragma unroll
    for (int t = 0; t < 4; t++)
      #pragma unroll
      for (int r = 0; r < 4; r++) mx = fmaxf(mx, sa[t][r]);
    mx = fmaxf(mx, __shfl_xor(mx, 16));
    mx = fmaxf(mx, __shfl_xor(mx, 32));
    if (!__all(mx <= m_run + DEFER_TH)){     // defer-max: rescale rarely
      float m_new = fmaxf(m_run, mx);
      float alpha = exp2f(m_run - m_new);    // first tile: exp2(-inf)=0
      l_run *= alpha;
      #pragma unroll
      for (int t = 0; t < 8; t++) o[t] *= alpha;
      m_run = m_new;
    }
    s16x4 pb[4];
    float lsum = 0.0f;
    #pragma unroll
    for (int t = 0; t < 4; t++)
      #pragma unroll
      for (int r = 0; r < 4; r++){
        float e = exp2f(sa[t][r] - m_run);
        pb[t][r] = f2bf(e);
        lsum += e;
      }
    lsum += __shfl_xor(lsum, 16);
    lsum += __shfl_xor(lsum, 32);
    l_run += lsum;

    // O^T += V^T * P^T (x16): A rows = dv, B = P straight from regs
    __builtin_amdgcn_s_setprio(1);
    #pragma unroll
    for (int dt = 0; dt < 8; dt++){
      #pragma unroll
      for (int t = 0; t < 4; t++){
        s16x4 va = *(const s16x4*)&Vs[dt*16 + lr][t*16 + 4*lg];
        o[dt] = MFMA16(va, pb[t], o[dt]);
      }
    }
    __builtin_amdgcn_s_setprio(0);

    if (it + 1 < NT){
      __syncthreads();                 // all waves done reading LDS
      #pragma unroll
      for (int j = 0; j < 4; j++){
        *(s16x8*)&Ks[kr][kc + 8*j] = kR[j];
        *(s16x8*)&Vs[vr][vc + 8*j] = vR[j];
      }
      __syncthreads();                 // LDS ready
    }
  }

  const int lg4 = lg * 4;
  const size_t grow = (size_t)b * S_LEN + qrow;
  float* Op = Opart + ((size_t)sp * NROWS + grow) * D_HEAD + lg4;
  #pragma unroll
  for (int dt = 0; dt < 8; dt++)
    *(f32x4*)(Op + dt * 16) = o[dt];
  if (lg == 0){
    float* ml = MLpart + ((size_t)sp * NROWS + grow) * 2;
    ml[0] = m_run; ml[1] = l_run;
  }
}

// ---------------------------------------------------------------------------
// Kernel 4: merge the NSPLIT partials (exp2 domain).
// ---------------------------------------------------------------------------
__global__ __launch_bounds__(256) void merge_kernel(
    const float* __restrict__ Opart, const float* __restrict__ MLpart,
    float* __restrict__ out){
  int idx = blockIdx.x * 256 + threadIdx.x;    // < 8192*128
  int row = idx >> 7;
  float m[NSPLIT], l[NSPLIT];
  float M = -INFINITY;
  #pragma unroll
  for (int s = 0; s < NSPLIT; s++){
    m[s] = MLpart[((size_t)s * NROWS + row) * 2 + 0];
    l[s] = MLpart[((size_t)s * NROWS + row) * 2 + 1];
    M = fmaxf(M, m[s]);
  }
  float L = 0.f, val = 0.f;
  #pragma unroll
  for (int s = 0; s < NSPLIT; s++){
    float e = exp2f(m[s] - M);
    L   += l[s] * e;
    val += Opart[(size_t)s * NROWS * D_HEAD + idx] * e;
  }
  out[idx] = val / L;
}

// ---------------------------------------------------------------------------
extern "C" void kernel_launch(void* const* d_in, const int* in_sizes, int n_in,
                              void* d_out, int out_size, void* d_ws, size_t ws_size,
                              hipStream_t stream){
  const float* X  = (const float*)d_in[0];
  const float* Wq = (const float*)d_in[1];
  const float* Wk = (const float*)d_in[2];
  const float* Wv = (const float*)d_in[3];
  char* ws = (char*)d_ws;
  short* Wt = (short*)(ws + WT_OFF);
  short* Qp = (short*)(ws + Q_OFF);
  short* Kp = (short*)(ws + K_OFF);
  short* Vt = (short*)(ws + V_OFF);
  float* Op = (float*)(ws + OP_OFF);
  float* Ml = (float*)(ws + ML_OFF);
  float* out = (float*)d_out;

  wt3_kernel  <<<dim3(1536),           dim3(256), 0, stream>>>(Wq, Wk, Wv, Wt);
  proj_kernel <<<dim3(128, 3),         dim3(256), 0, stream>>>(X, Wt, Qp, Kp, Vt);
  flash_kernel<<<dim3(NSPLIT, 32, 4),  dim3(256), 0, stream>>>(Qp, Kp, Vt, Op, Ml);
  merge_kernel<<<dim3(4096),           dim3(256), 0, stream>>>(Op, Ml, out);
}